// Round 1
// baseline (1536.090 us; speedup 1.0000x reference)
//
#include <hip/hip_runtime.h>

// SimpleRecGNN: 6-layer GCN, N=200000 nodes, E=2000000 edges, dims 16->32(x5)->16.
// Strategy: build CSR (grouped by destination col) once per launch, precompute
// per-edge norm; per layer do propagate (gather) + dense transform (W in LDS).
// Uses linearity: agg(hW * norm) == agg(h * norm) W, so propagate in the
// smaller dim for layers 0 and 5.

namespace {

constexpr int kUsers = 100000;
constexpr int kBooks = 100000;
constexpr int kN = kUsers + kBooks;
constexpr int kE = 2000000;
constexpr int BLK = 256;

__global__ void init_kernel(float* __restrict__ deg, int* __restrict__ cnt,
                            int* __restrict__ fill) {
  int stride = gridDim.x * blockDim.x;
  for (int i = blockIdx.x * blockDim.x + threadIdx.x; i < kN; i += stride) {
    deg[i] = 1.0f;  // self-loop weight
    cnt[i] = 0;
    fill[i] = 0;
  }
}

__global__ void embed_kernel(const int* __restrict__ x,
                             const float* __restrict__ uemb,
                             const float* __restrict__ bemb,
                             float* __restrict__ h) {
  int stride = gridDim.x * blockDim.x;
  for (int idx = blockIdx.x * blockDim.x + threadIdx.x; idx < kN * 16;
       idx += stride) {
    int node = idx >> 4;
    int d = idx & 15;
    int nid = x[node * 2];
    int typ = x[node * 2 + 1];
    float v;
    if (typ == 0) {
      int c = min(max(nid, 0), kUsers - 1);
      v = uemb[c * 16 + d];
    } else {
      int c = min(max(nid - kUsers, 0), kBooks - 1);
      v = bemb[c * 16 + d];
    }
    h[idx] = v;
  }
}

__global__ void edge_count_kernel(const int* __restrict__ ei,
                                  const float* __restrict__ ew,
                                  float* __restrict__ deg,
                                  int* __restrict__ cnt) {
  int stride = gridDim.x * blockDim.x;
  for (int i = blockIdx.x * blockDim.x + threadIdx.x; i < kE; i += stride) {
    int c = ei[kE + i];  // edge_index[1][i]
    atomicAdd(&deg[c], ew[i]);
    atomicAdd(&cnt[c], 1);
  }
}

// in-place deg -> dinv
__global__ void dinv_kernel(float* __restrict__ degdinv) {
  int stride = gridDim.x * blockDim.x;
  for (int i = blockIdx.x * blockDim.x + threadIdx.x; i < kN; i += stride) {
    float dg = degdinv[i];
    degdinv[i] = dg > 0.f ? rsqrtf(fmaxf(dg, 1e-12f)) : 0.f;
  }
}

// single-block exclusive scan of cnt[0..kN) into row_ptr[0..kN]
__global__ void __launch_bounds__(1024) scan_kernel(const int* __restrict__ cnt,
                                                    int* __restrict__ row_ptr) {
  constexpr int T = 1024;
  __shared__ int s[T];
  int tid = threadIdx.x;
  int chunk = (kN + T - 1) / T;
  int beg = tid * chunk;
  int end = min(beg + chunk, kN);
  int sum = 0;
  for (int i = beg; i < end; ++i) sum += cnt[i];
  s[tid] = sum;
  __syncthreads();
  // Hillis-Steele inclusive scan
  for (int off = 1; off < T; off <<= 1) {
    int v = (tid >= off) ? s[tid - off] : 0;
    __syncthreads();
    s[tid] += v;
    __syncthreads();
  }
  int run = (tid == 0) ? 0 : s[tid - 1];
  for (int i = beg; i < end; ++i) {
    row_ptr[i] = run;
    run += cnt[i];
  }
  if (tid == T - 1) row_ptr[kN] = run;  // == kE
}

__global__ void scatter_kernel(const int* __restrict__ ei,
                               const float* __restrict__ ew,
                               const float* __restrict__ dinv,
                               const int* __restrict__ row_ptr,
                               int* __restrict__ fill,
                               int* __restrict__ csr_src,
                               float* __restrict__ csr_nrm) {
  int stride = gridDim.x * blockDim.x;
  for (int i = blockIdx.x * blockDim.x + threadIdx.x; i < kE; i += stride) {
    int r = ei[i];
    int c = ei[kE + i];
    int pos = row_ptr[c] + atomicAdd(&fill[c], 1);
    csr_src[pos] = r;
    csr_nrm[pos] = dinv[r] * ew[i] * dinv[c];
  }
}

// out[i,d] = sum_{e in in-edges(i)} h[src(e),d]*norm(e) + h[i,d]*dinv[i]^2 (+bias)
template <int DIN, bool ADD_BIAS>
__global__ void propagate_kernel(const float* __restrict__ h,
                                 float* __restrict__ out,
                                 const int* __restrict__ row_ptr,
                                 const int* __restrict__ csr_src,
                                 const float* __restrict__ csr_nrm,
                                 const float* __restrict__ dinv,
                                 const float* __restrict__ bias) {
  int stride = gridDim.x * blockDim.x;
  constexpr int total = kN * DIN;
  for (int idx = blockIdx.x * blockDim.x + threadIdx.x; idx < total;
       idx += stride) {
    int node = idx / DIN;
    int d = idx - node * DIN;
    float di = dinv[node];
    float acc = h[idx] * di * di;  // self-loop
    int beg = row_ptr[node];
    int end = row_ptr[node + 1];
    for (int e = beg; e < end; ++e) {
      acc = fmaf(h[csr_src[e] * DIN + d], csr_nrm[e], acc);
    }
    if (ADD_BIAS) acc += bias[d];
    out[idx] = acc;
  }
}

// out[i,:] = h[i,:] @ W (+bias) (relu)
template <int DIN, int DOUT, bool RELU, bool ADD_BIAS>
__global__ void transform_kernel(const float* __restrict__ h,
                                 const float* __restrict__ W,
                                 const float* __restrict__ bias,
                                 float* __restrict__ out) {
  __shared__ float sW[DIN * DOUT];
  for (int i = threadIdx.x; i < DIN * DOUT; i += blockDim.x) sW[i] = W[i];
  __syncthreads();
  int stride = gridDim.x * blockDim.x;
  constexpr int total = kN * DOUT;
  for (int idx = blockIdx.x * blockDim.x + threadIdx.x; idx < total;
       idx += stride) {
    int node = idx / DOUT;
    int d = idx - node * DOUT;
    float acc = ADD_BIAS ? bias[d] : 0.f;
    const float* hrow = h + node * DIN;
#pragma unroll
    for (int k = 0; k < DIN; ++k) acc = fmaf(hrow[k], sW[k * DOUT + d], acc);
    if (RELU) acc = fmaxf(acc, 0.f);
    out[idx] = acc;
  }
}

inline int cdiv(long a, long b) { return (int)((a + b - 1) / b); }

}  // namespace

extern "C" void kernel_launch(void* const* d_in, const int* in_sizes, int n_in,
                              void* d_out, int out_size, void* d_ws,
                              size_t ws_size, hipStream_t stream) {
  const int* x = (const int*)d_in[0];
  const int* ei = (const int*)d_in[1];
  const float* ew = (const float*)d_in[2];
  const float* uemb = (const float*)d_in[3];
  const float* bemb = (const float*)d_in[4];
  const float* W0 = (const float*)d_in[5];
  const float* b0 = (const float*)d_in[6];
  const float* W1 = (const float*)d_in[7];
  const float* b1 = (const float*)d_in[8];
  const float* W2 = (const float*)d_in[9];
  const float* b2 = (const float*)d_in[10];
  const float* W3 = (const float*)d_in[11];
  const float* b3 = (const float*)d_in[12];
  const float* W4 = (const float*)d_in[13];
  const float* b4 = (const float*)d_in[14];
  const float* W5 = (const float*)d_in[15];
  const float* b5 = (const float*)d_in[16];
  float* out = (float*)d_out;

  // Workspace carve-up (~70.5 MB total)
  char* ws = (char*)d_ws;
  size_t off = 0;
  auto walloc = [&](size_t bytes) -> void* {
    void* p = ws + off;
    off += (bytes + 255) & ~size_t(255);
    return p;
  };
  float* degdinv = (float*)walloc((size_t)kN * 4);
  int* cnt = (int*)walloc((size_t)kN * 4);
  int* fill = (int*)walloc((size_t)kN * 4);
  int* row_ptr = (int*)walloc((size_t)(kN + 1) * 4);
  int* csr_src = (int*)walloc((size_t)kE * 4);
  float* csr_nrm = (float*)walloc((size_t)kE * 4);
  float* hA = (float*)walloc((size_t)kN * 32 * 4);
  float* hB = (float*)walloc((size_t)kN * 32 * 4);
  (void)ws_size;
  (void)in_sizes;
  (void)n_in;
  (void)out_size;

  // --- graph prep ---
  init_kernel<<<cdiv(kN, BLK), BLK, 0, stream>>>(degdinv, cnt, fill);
  embed_kernel<<<cdiv(kN * 16, BLK), BLK, 0, stream>>>(x, uemb, bemb, hA);
  edge_count_kernel<<<cdiv(kE, BLK), BLK, 0, stream>>>(ei, ew, degdinv, cnt);
  dinv_kernel<<<cdiv(kN, BLK), BLK, 0, stream>>>(degdinv);
  scan_kernel<<<1, 1024, 0, stream>>>(cnt, row_ptr);
  scatter_kernel<<<cdiv(kE, BLK), BLK, 0, stream>>>(ei, ew, degdinv, row_ptr,
                                                    fill, csr_src, csr_nrm);

  // --- layer 0: propagate in 16-dim, then 16->32 transform (+b0, relu) ---
  propagate_kernel<16, false><<<cdiv(kN * 16, BLK), BLK, 0, stream>>>(
      hA, hB, row_ptr, csr_src, csr_nrm, degdinv, nullptr);
  transform_kernel<16, 32, true, true><<<cdiv(kN * 32, BLK), BLK, 0, stream>>>(
      hB, W0, b0, hA);

  // --- layers 1..4: propagate 32-dim, transform 32->32 (+b, relu) ---
  const float* Ws[4] = {W1, W2, W3, W4};
  const float* Bs[4] = {b1, b2, b3, b4};
  for (int l = 0; l < 4; ++l) {
    propagate_kernel<32, false><<<cdiv(kN * 32, BLK), BLK, 0, stream>>>(
        hA, hB, row_ptr, csr_src, csr_nrm, degdinv, nullptr);
    transform_kernel<32, 32, true, true>
        <<<cdiv(kN * 32, BLK), BLK, 0, stream>>>(hB, Ws[l], Bs[l], hA);
  }

  // --- layer 5: transform 32->16 first (no bias/relu), then propagate (+b5) ---
  transform_kernel<32, 16, false, false>
      <<<cdiv(kN * 16, BLK), BLK, 0, stream>>>(hA, W5, nullptr, hB);
  propagate_kernel<16, true><<<cdiv(kN * 16, BLK), BLK, 0, stream>>>(
      hB, out, row_ptr, csr_src, csr_nrm, degdinv, b5);
}

// Round 2
// 1201.325 us; speedup vs baseline: 1.2787x; 1.2787x over previous
//
#include <hip/hip_runtime.h>

// SimpleRecGNN: 6-layer GCN, N=200000 nodes, E=2000000 edges, dims 16->32(x5)->16.
// CSR built per launch (count -> 3-kernel device scan -> scatter), per-edge norm
// precomputed; per layer: propagate (gather) + dense transform (W in LDS).
// Linearity: agg(hW * norm) == agg(h * norm) W, so propagate in the smaller
// dim for layers 0 and 5.

namespace {

constexpr int kUsers = 100000;
constexpr int kBooks = 100000;
constexpr int kN = kUsers + kBooks;
constexpr int kE = 2000000;
constexpr int BLK = 256;

// ---- device-wide exclusive scan of cnt[kN] -> row_ptr[kN+1] ----
// Each scan block covers SCAN_ELEMS = 256 threads * 4 elems = 1024 elements.
constexpr int SCAN_T = 256;
constexpr int SCAN_PER_THREAD = 4;
constexpr int SCAN_ELEMS = SCAN_T * SCAN_PER_THREAD;  // 1024
constexpr int SCAN_BLOCKS = (kN + SCAN_ELEMS - 1) / SCAN_ELEMS;  // 196

__global__ void init_kernel(float* __restrict__ deg, int* __restrict__ cnt,
                            int* __restrict__ fill) {
  int stride = gridDim.x * blockDim.x;
  for (int i = blockIdx.x * blockDim.x + threadIdx.x; i < kN; i += stride) {
    deg[i] = 1.0f;  // self-loop weight
    cnt[i] = 0;
    fill[i] = 0;
  }
}

__global__ void embed_kernel(const int* __restrict__ x,
                             const float* __restrict__ uemb,
                             const float* __restrict__ bemb,
                             float* __restrict__ h) {
  int stride = gridDim.x * blockDim.x;
  for (int idx = blockIdx.x * blockDim.x + threadIdx.x; idx < kN * 16;
       idx += stride) {
    int node = idx >> 4;
    int d = idx & 15;
    int nid = x[node * 2];
    int typ = x[node * 2 + 1];
    float v;
    if (typ == 0) {
      int c = min(max(nid, 0), kUsers - 1);
      v = uemb[c * 16 + d];
    } else {
      int c = min(max(nid - kUsers, 0), kBooks - 1);
      v = bemb[c * 16 + d];
    }
    h[idx] = v;
  }
}

__global__ void edge_count_kernel(const int* __restrict__ ei,
                                  const float* __restrict__ ew,
                                  float* __restrict__ deg,
                                  int* __restrict__ cnt) {
  int stride = gridDim.x * blockDim.x;
  for (int i = blockIdx.x * blockDim.x + threadIdx.x; i < kE; i += stride) {
    int c = ei[kE + i];  // edge_index[1][i]
    atomicAdd(&deg[c], ew[i]);
    atomicAdd(&cnt[c], 1);
  }
}

// in-place deg -> dinv
__global__ void dinv_kernel(float* __restrict__ degdinv) {
  int stride = gridDim.x * blockDim.x;
  for (int i = blockIdx.x * blockDim.x + threadIdx.x; i < kN; i += stride) {
    float dg = degdinv[i];
    degdinv[i] = dg > 0.f ? rsqrtf(fmaxf(dg, 1e-12f)) : 0.f;
  }
}

// pass 1: per-block partial sums
__global__ void __launch_bounds__(SCAN_T) scan_part_kernel(
    const int* __restrict__ cnt, int* __restrict__ bsum) {
  __shared__ int s[SCAN_T];
  int b = blockIdx.x;
  int t = threadIdx.x;
  int base = b * SCAN_ELEMS + t * SCAN_PER_THREAD;
  int sum = 0;
#pragma unroll
  for (int j = 0; j < SCAN_PER_THREAD; ++j) {
    int i = base + j;
    if (i < kN) sum += cnt[i];
  }
  s[t] = sum;
  __syncthreads();
  for (int off = SCAN_T / 2; off > 0; off >>= 1) {
    if (t < off) s[t] += s[t + off];
    __syncthreads();
  }
  if (t == 0) bsum[b] = s[0];
}

// pass 2: single block exclusive scan of bsum[SCAN_BLOCKS] -> boff
__global__ void __launch_bounds__(SCAN_T) scan_mid_kernel(
    const int* __restrict__ bsum, int* __restrict__ boff,
    int* __restrict__ row_ptr) {
  __shared__ int s[SCAN_T];
  int t = threadIdx.x;
  int v = (t < SCAN_BLOCKS) ? bsum[t] : 0;
  s[t] = v;
  __syncthreads();
  // Hillis-Steele inclusive
  for (int off = 1; off < SCAN_T; off <<= 1) {
    int add = (t >= off) ? s[t - off] : 0;
    __syncthreads();
    s[t] += add;
    __syncthreads();
  }
  if (t < SCAN_BLOCKS) boff[t] = (t == 0) ? 0 : s[t - 1];
  if (t == SCAN_T - 1) row_ptr[kN] = s[SCAN_T - 1];  // total == kE
}

// pass 3: per-block local exclusive scan + block offset -> row_ptr
__global__ void __launch_bounds__(SCAN_T) scan_final_kernel(
    const int* __restrict__ cnt, const int* __restrict__ boff,
    int* __restrict__ row_ptr) {
  __shared__ int s[SCAN_T];
  int b = blockIdx.x;
  int t = threadIdx.x;
  int base = b * SCAN_ELEMS + t * SCAN_PER_THREAD;
  int v[SCAN_PER_THREAD];
  int sum = 0;
#pragma unroll
  for (int j = 0; j < SCAN_PER_THREAD; ++j) {
    int i = base + j;
    v[j] = (i < kN) ? cnt[i] : 0;
    sum += v[j];
  }
  s[t] = sum;
  __syncthreads();
  for (int off = 1; off < SCAN_T; off <<= 1) {
    int add = (t >= off) ? s[t - off] : 0;
    __syncthreads();
    s[t] += add;
    __syncthreads();
  }
  int run = boff[b] + ((t == 0) ? 0 : s[t - 1]);
#pragma unroll
  for (int j = 0; j < SCAN_PER_THREAD; ++j) {
    int i = base + j;
    if (i < kN) row_ptr[i] = run;
    run += v[j];
  }
}

__global__ void scatter_kernel(const int* __restrict__ ei,
                               const float* __restrict__ ew,
                               const float* __restrict__ dinv,
                               const int* __restrict__ row_ptr,
                               int* __restrict__ fill,
                               int* __restrict__ csr_src,
                               float* __restrict__ csr_nrm) {
  int stride = gridDim.x * blockDim.x;
  for (int i = blockIdx.x * blockDim.x + threadIdx.x; i < kE; i += stride) {
    int r = ei[i];
    int c = ei[kE + i];
    int pos = row_ptr[c] + atomicAdd(&fill[c], 1);
    csr_src[pos] = r;
    csr_nrm[pos] = dinv[r] * ew[i] * dinv[c];
  }
}

// out[i,d] = sum_{e in in-edges(i)} h[src(e),d]*norm(e) + h[i,d]*dinv[i]^2 (+bias)
template <int DIN, bool ADD_BIAS>
__global__ void propagate_kernel(const float* __restrict__ h,
                                 float* __restrict__ out,
                                 const int* __restrict__ row_ptr,
                                 const int* __restrict__ csr_src,
                                 const float* __restrict__ csr_nrm,
                                 const float* __restrict__ dinv,
                                 const float* __restrict__ bias) {
  int stride = gridDim.x * blockDim.x;
  constexpr int total = kN * DIN;
  for (int idx = blockIdx.x * blockDim.x + threadIdx.x; idx < total;
       idx += stride) {
    int node = idx / DIN;
    int d = idx - node * DIN;
    float di = dinv[node];
    float acc = h[idx] * di * di;  // self-loop
    int beg = row_ptr[node];
    int end = row_ptr[node + 1];
    for (int e = beg; e < end; ++e) {
      acc = fmaf(h[csr_src[e] * DIN + d], csr_nrm[e], acc);
    }
    if (ADD_BIAS) acc += bias[d];
    out[idx] = acc;
  }
}

// out[i,:] = h[i,:] @ W (+bias) (relu)
template <int DIN, int DOUT, bool RELU, bool ADD_BIAS>
__global__ void transform_kernel(const float* __restrict__ h,
                                 const float* __restrict__ W,
                                 const float* __restrict__ bias,
                                 float* __restrict__ out) {
  __shared__ float sW[DIN * DOUT];
  for (int i = threadIdx.x; i < DIN * DOUT; i += blockDim.x) sW[i] = W[i];
  __syncthreads();
  int stride = gridDim.x * blockDim.x;
  constexpr int total = kN * DOUT;
  for (int idx = blockIdx.x * blockDim.x + threadIdx.x; idx < total;
       idx += stride) {
    int node = idx / DOUT;
    int d = idx - node * DOUT;
    float acc = ADD_BIAS ? bias[d] : 0.f;
    const float* hrow = h + node * DIN;
#pragma unroll
    for (int k = 0; k < DIN; ++k) acc = fmaf(hrow[k], sW[k * DOUT + d], acc);
    if (RELU) acc = fmaxf(acc, 0.f);
    out[idx] = acc;
  }
}

inline int cdiv(long a, long b) { return (int)((a + b - 1) / b); }

}  // namespace

extern "C" void kernel_launch(void* const* d_in, const int* in_sizes, int n_in,
                              void* d_out, int out_size, void* d_ws,
                              size_t ws_size, hipStream_t stream) {
  const int* x = (const int*)d_in[0];
  const int* ei = (const int*)d_in[1];
  const float* ew = (const float*)d_in[2];
  const float* uemb = (const float*)d_in[3];
  const float* bemb = (const float*)d_in[4];
  const float* W0 = (const float*)d_in[5];
  const float* b0 = (const float*)d_in[6];
  const float* W1 = (const float*)d_in[7];
  const float* b1 = (const float*)d_in[8];
  const float* W2 = (const float*)d_in[9];
  const float* b2 = (const float*)d_in[10];
  const float* W3 = (const float*)d_in[11];
  const float* b3 = (const float*)d_in[12];
  const float* W4 = (const float*)d_in[13];
  const float* b4 = (const float*)d_in[14];
  const float* W5 = (const float*)d_in[15];
  const float* b5 = (const float*)d_in[16];
  float* out = (float*)d_out;

  // Workspace carve-up (~70.5 MB total)
  char* ws = (char*)d_ws;
  size_t off = 0;
  auto walloc = [&](size_t bytes) -> void* {
    void* p = ws + off;
    off += (bytes + 255) & ~size_t(255);
    return p;
  };
  float* degdinv = (float*)walloc((size_t)kN * 4);
  int* cnt = (int*)walloc((size_t)kN * 4);
  int* fill = (int*)walloc((size_t)kN * 4);
  int* row_ptr = (int*)walloc((size_t)(kN + 1) * 4);
  int* bsum = (int*)walloc((size_t)SCAN_BLOCKS * 4);
  int* boff = (int*)walloc((size_t)SCAN_BLOCKS * 4);
  int* csr_src = (int*)walloc((size_t)kE * 4);
  float* csr_nrm = (float*)walloc((size_t)kE * 4);
  float* hA = (float*)walloc((size_t)kN * 32 * 4);
  float* hB = (float*)walloc((size_t)kN * 32 * 4);
  (void)ws_size;
  (void)in_sizes;
  (void)n_in;
  (void)out_size;

  // --- graph prep ---
  init_kernel<<<cdiv(kN, BLK), BLK, 0, stream>>>(degdinv, cnt, fill);
  embed_kernel<<<cdiv(kN * 16, BLK), BLK, 0, stream>>>(x, uemb, bemb, hA);
  edge_count_kernel<<<cdiv(kE, BLK), BLK, 0, stream>>>(ei, ew, degdinv, cnt);
  dinv_kernel<<<cdiv(kN, BLK), BLK, 0, stream>>>(degdinv);
  scan_part_kernel<<<SCAN_BLOCKS, SCAN_T, 0, stream>>>(cnt, bsum);
  scan_mid_kernel<<<1, SCAN_T, 0, stream>>>(bsum, boff, row_ptr);
  scan_final_kernel<<<SCAN_BLOCKS, SCAN_T, 0, stream>>>(cnt, boff, row_ptr);
  scatter_kernel<<<cdiv(kE, BLK), BLK, 0, stream>>>(ei, ew, degdinv, row_ptr,
                                                    fill, csr_src, csr_nrm);

  // --- layer 0: propagate in 16-dim, then 16->32 transform (+b0, relu) ---
  propagate_kernel<16, false><<<cdiv(kN * 16, BLK), BLK, 0, stream>>>(
      hA, hB, row_ptr, csr_src, csr_nrm, degdinv, nullptr);
  transform_kernel<16, 32, true, true><<<cdiv(kN * 32, BLK), BLK, 0, stream>>>(
      hB, W0, b0, hA);

  // --- layers 1..4: propagate 32-dim, transform 32->32 (+b, relu) ---
  const float* Ws[4] = {W1, W2, W3, W4};
  const float* Bs[4] = {b1, b2, b3, b4};
  for (int l = 0; l < 4; ++l) {
    propagate_kernel<32, false><<<cdiv(kN * 32, BLK), BLK, 0, stream>>>(
        hA, hB, row_ptr, csr_src, csr_nrm, degdinv, nullptr);
    transform_kernel<32, 32, true, true>
        <<<cdiv(kN * 32, BLK), BLK, 0, stream>>>(hB, Ws[l], Bs[l], hA);
  }

  // --- layer 5: transform 32->16 first (no bias/relu), then propagate (+b5) ---
  transform_kernel<32, 16, false, false>
      <<<cdiv(kN * 16, BLK), BLK, 0, stream>>>(hA, W5, nullptr, hB);
  propagate_kernel<16, true><<<cdiv(kN * 16, BLK), BLK, 0, stream>>>(
      hB, out, row_ptr, csr_src, csr_nrm, degdinv, b5);
}

// Round 3
// 1162.062 us; speedup vs baseline: 1.3219x; 1.0338x over previous
//
#include <hip/hip_runtime.h>

// SimpleRecGNN: 6-layer GCN, N=200000 nodes, E=2000000 edges, dims 16->32(x5)->16.
// CSR built per launch (int-only count -> 3-kernel device scan -> scatter),
// deg/dinv computed atomic-free from CSR rows, per-edge norm in place.
// Per layer: propagate (gather) + dense transform (W in LDS).
// Linearity: agg(hW * norm) == agg(h * norm) W, so propagate in the smaller
// dim for layers 0 and 5.

namespace {

constexpr int kUsers = 100000;
constexpr int kBooks = 100000;
constexpr int kN = kUsers + kBooks;
constexpr int kE = 2000000;
constexpr int BLK = 256;

constexpr int SCAN_T = 256;
constexpr int SCAN_PER_THREAD = 4;
constexpr int SCAN_ELEMS = SCAN_T * SCAN_PER_THREAD;  // 1024
constexpr int SCAN_BLOCKS = (kN + SCAN_ELEMS - 1) / SCAN_ELEMS;  // 196

__global__ void init_kernel(int* __restrict__ cnt) {
  int stride = gridDim.x * blockDim.x;
  for (int i = blockIdx.x * blockDim.x + threadIdx.x; i < kN; i += stride) {
    cnt[i] = 0;
  }
}

__global__ void embed_kernel(const int* __restrict__ x,
                             const float* __restrict__ uemb,
                             const float* __restrict__ bemb,
                             float* __restrict__ h) {
  int stride = gridDim.x * blockDim.x;
  for (int idx = blockIdx.x * blockDim.x + threadIdx.x; idx < kN * 16;
       idx += stride) {
    int node = idx >> 4;
    int d = idx & 15;
    int nid = x[node * 2];
    int typ = x[node * 2 + 1];
    float v;
    if (typ == 0) {
      int c = min(max(nid, 0), kUsers - 1);
      v = uemb[c * 16 + d];
    } else {
      int c = min(max(nid - kUsers, 0), kBooks - 1);
      v = bemb[c * 16 + d];
    }
    h[idx] = v;
  }
}

// count in-edges per destination (int4-vectorized reads, int atomics only)
__global__ void edge_count_kernel(const int* __restrict__ ei_col,
                                  int* __restrict__ cnt) {
  int stride = gridDim.x * blockDim.x;
  constexpr int quarter = kE / 4;
  const int4* col4 = (const int4*)ei_col;
  for (int i = blockIdx.x * blockDim.x + threadIdx.x; i < quarter;
       i += stride) {
    int4 c = col4[i];
    atomicAdd(&cnt[c.x], 1);
    atomicAdd(&cnt[c.y], 1);
    atomicAdd(&cnt[c.z], 1);
    atomicAdd(&cnt[c.w], 1);
  }
}

// pass 1: per-block partial sums
__global__ void __launch_bounds__(SCAN_T) scan_part_kernel(
    const int* __restrict__ cnt, int* __restrict__ bsum) {
  __shared__ int s[SCAN_T];
  int b = blockIdx.x;
  int t = threadIdx.x;
  int base = b * SCAN_ELEMS + t * SCAN_PER_THREAD;
  int sum = 0;
#pragma unroll
  for (int j = 0; j < SCAN_PER_THREAD; ++j) {
    int i = base + j;
    if (i < kN) sum += cnt[i];
  }
  s[t] = sum;
  __syncthreads();
  for (int off = SCAN_T / 2; off > 0; off >>= 1) {
    if (t < off) s[t] += s[t + off];
    __syncthreads();
  }
  if (t == 0) bsum[b] = s[0];
}

// pass 2: single block exclusive scan of bsum[SCAN_BLOCKS] -> boff
__global__ void __launch_bounds__(SCAN_T) scan_mid_kernel(
    const int* __restrict__ bsum, int* __restrict__ boff,
    int* __restrict__ row_ptr) {
  __shared__ int s[SCAN_T];
  int t = threadIdx.x;
  int v = (t < SCAN_BLOCKS) ? bsum[t] : 0;
  s[t] = v;
  __syncthreads();
  for (int off = 1; off < SCAN_T; off <<= 1) {
    int add = (t >= off) ? s[t - off] : 0;
    __syncthreads();
    s[t] += add;
    __syncthreads();
  }
  if (t < SCAN_BLOCKS) boff[t] = (t == 0) ? 0 : s[t - 1];
  if (t == SCAN_T - 1) row_ptr[kN] = s[SCAN_T - 1];  // total == kE
}

// pass 3: per-block local exclusive scan + block offset -> row_ptr AND fill
__global__ void __launch_bounds__(SCAN_T) scan_final_kernel(
    const int* __restrict__ cnt, const int* __restrict__ boff,
    int* __restrict__ row_ptr, int* __restrict__ fill) {
  __shared__ int s[SCAN_T];
  int b = blockIdx.x;
  int t = threadIdx.x;
  int base = b * SCAN_ELEMS + t * SCAN_PER_THREAD;
  int v[SCAN_PER_THREAD];
  int sum = 0;
#pragma unroll
  for (int j = 0; j < SCAN_PER_THREAD; ++j) {
    int i = base + j;
    v[j] = (i < kN) ? cnt[i] : 0;
    sum += v[j];
  }
  s[t] = sum;
  __syncthreads();
  for (int off = 1; off < SCAN_T; off <<= 1) {
    int add = (t >= off) ? s[t - off] : 0;
    __syncthreads();
    s[t] += add;
    __syncthreads();
  }
  int run = boff[b] + ((t == 0) ? 0 : s[t - 1]);
#pragma unroll
  for (int j = 0; j < SCAN_PER_THREAD; ++j) {
    int i = base + j;
    if (i < kN) {
      row_ptr[i] = run;
      fill[i] = run;
    }
    run += v[j];
  }
}

// scatter edges into CSR slots; fill[] was pre-set to row_ptr values.
// Stores raw edge weight into csr_nrm (norm finalized later).
__global__ void scatter_kernel(const int* __restrict__ ei,
                               const float* __restrict__ ew,
                               int* __restrict__ fill,
                               int* __restrict__ csr_src,
                               float* __restrict__ csr_nrm) {
  int stride = gridDim.x * blockDim.x;
  for (int i = blockIdx.x * blockDim.x + threadIdx.x; i < kE; i += stride) {
    int r = ei[i];
    int c = ei[kE + i];
    int pos = atomicAdd(&fill[c], 1);
    csr_src[pos] = r;
    csr_nrm[pos] = ew[i];
  }
}

// per node: deg = 1 + sum of row weights; dinv = rsqrt
__global__ void deg_dinv_kernel(const int* __restrict__ row_ptr,
                                const float* __restrict__ csr_w,
                                float* __restrict__ dinv) {
  int stride = gridDim.x * blockDim.x;
  for (int i = blockIdx.x * blockDim.x + threadIdx.x; i < kN; i += stride) {
    int beg = row_ptr[i];
    int end = row_ptr[i + 1];
    float s = 1.0f;  // self-loop
    for (int e = beg; e < end; ++e) s += csr_w[e];
    dinv[i] = s > 0.f ? rsqrtf(fmaxf(s, 1e-12f)) : 0.f;
  }
}

// per node: csr_nrm[e] = dinv[src]*w*dinv[col]  (in place over csr_w)
__global__ void norm_kernel(const int* __restrict__ row_ptr,
                            const int* __restrict__ csr_src,
                            float* __restrict__ csr_nrm,
                            const float* __restrict__ dinv) {
  int stride = gridDim.x * blockDim.x;
  for (int i = blockIdx.x * blockDim.x + threadIdx.x; i < kN; i += stride) {
    int beg = row_ptr[i];
    int end = row_ptr[i + 1];
    float di = dinv[i];
    for (int e = beg; e < end; ++e) {
      csr_nrm[e] = dinv[csr_src[e]] * csr_nrm[e] * di;
    }
  }
}

// out[i,d] = sum_{e in in-edges(i)} h[src(e),d]*norm(e) + h[i,d]*dinv[i]^2 (+bias)
template <int DIN, bool ADD_BIAS>
__global__ void propagate_kernel(const float* __restrict__ h,
                                 float* __restrict__ out,
                                 const int* __restrict__ row_ptr,
                                 const int* __restrict__ csr_src,
                                 const float* __restrict__ csr_nrm,
                                 const float* __restrict__ dinv,
                                 const float* __restrict__ bias) {
  int stride = gridDim.x * blockDim.x;
  constexpr int total = kN * DIN;
  for (int idx = blockIdx.x * blockDim.x + threadIdx.x; idx < total;
       idx += stride) {
    int node = idx / DIN;
    int d = idx - node * DIN;
    float di = dinv[node];
    float acc = h[idx] * di * di;  // self-loop
    int beg = row_ptr[node];
    int end = row_ptr[node + 1];
    for (int e = beg; e < end; ++e) {
      acc = fmaf(h[csr_src[e] * DIN + d], csr_nrm[e], acc);
    }
    if (ADD_BIAS) acc += bias[d];
    out[idx] = acc;
  }
}

// out[i,:] = h[i,:] @ W (+bias) (relu)
template <int DIN, int DOUT, bool RELU, bool ADD_BIAS>
__global__ void transform_kernel(const float* __restrict__ h,
                                 const float* __restrict__ W,
                                 const float* __restrict__ bias,
                                 float* __restrict__ out) {
  __shared__ float sW[DIN * DOUT];
  for (int i = threadIdx.x; i < DIN * DOUT; i += blockDim.x) sW[i] = W[i];
  __syncthreads();
  int stride = gridDim.x * blockDim.x;
  constexpr int total = kN * DOUT;
  for (int idx = blockIdx.x * blockDim.x + threadIdx.x; idx < total;
       idx += stride) {
    int node = idx / DOUT;
    int d = idx - node * DOUT;
    float acc = ADD_BIAS ? bias[d] : 0.f;
    const float* hrow = h + node * DIN;
#pragma unroll
    for (int k = 0; k < DIN; ++k) acc = fmaf(hrow[k], sW[k * DOUT + d], acc);
    if (RELU) acc = fmaxf(acc, 0.f);
    out[idx] = acc;
  }
}

inline int cdiv(long a, long b) { return (int)((a + b - 1) / b); }

}  // namespace

extern "C" void kernel_launch(void* const* d_in, const int* in_sizes, int n_in,
                              void* d_out, int out_size, void* d_ws,
                              size_t ws_size, hipStream_t stream) {
  const int* x = (const int*)d_in[0];
  const int* ei = (const int*)d_in[1];
  const float* ew = (const float*)d_in[2];
  const float* uemb = (const float*)d_in[3];
  const float* bemb = (const float*)d_in[4];
  const float* W0 = (const float*)d_in[5];
  const float* b0 = (const float*)d_in[6];
  const float* W1 = (const float*)d_in[7];
  const float* b1 = (const float*)d_in[8];
  const float* W2 = (const float*)d_in[9];
  const float* b2 = (const float*)d_in[10];
  const float* W3 = (const float*)d_in[11];
  const float* b3 = (const float*)d_in[12];
  const float* W4 = (const float*)d_in[13];
  const float* b4 = (const float*)d_in[14];
  const float* W5 = (const float*)d_in[15];
  const float* b5 = (const float*)d_in[16];
  float* out = (float*)d_out;

  char* ws = (char*)d_ws;
  size_t off = 0;
  auto walloc = [&](size_t bytes) -> void* {
    void* p = ws + off;
    off += (bytes + 255) & ~size_t(255);
    return p;
  };
  float* dinv = (float*)walloc((size_t)kN * 4);
  int* cnt = (int*)walloc((size_t)kN * 4);
  int* fill = (int*)walloc((size_t)kN * 4);
  int* row_ptr = (int*)walloc((size_t)(kN + 1) * 4);
  int* bsum = (int*)walloc((size_t)SCAN_BLOCKS * 4);
  int* boff = (int*)walloc((size_t)SCAN_BLOCKS * 4);
  int* csr_src = (int*)walloc((size_t)kE * 4);
  float* csr_nrm = (float*)walloc((size_t)kE * 4);
  float* hA = (float*)walloc((size_t)kN * 32 * 4);
  float* hB = (float*)walloc((size_t)kN * 32 * 4);
  (void)ws_size;
  (void)in_sizes;
  (void)n_in;
  (void)out_size;

  // --- graph prep ---
  init_kernel<<<cdiv(kN, BLK), BLK, 0, stream>>>(cnt);
  embed_kernel<<<cdiv(kN * 16, BLK), BLK, 0, stream>>>(x, uemb, bemb, hA);
  edge_count_kernel<<<cdiv(kE / 4, BLK), BLK, 0, stream>>>(ei + kE, cnt);
  scan_part_kernel<<<SCAN_BLOCKS, SCAN_T, 0, stream>>>(cnt, bsum);
  scan_mid_kernel<<<1, SCAN_T, 0, stream>>>(bsum, boff, row_ptr);
  scan_final_kernel<<<SCAN_BLOCKS, SCAN_T, 0, stream>>>(cnt, boff, row_ptr,
                                                        fill);
  scatter_kernel<<<cdiv(kE, BLK), BLK, 0, stream>>>(ei, ew, fill, csr_src,
                                                    csr_nrm);
  deg_dinv_kernel<<<cdiv(kN, BLK), BLK, 0, stream>>>(row_ptr, csr_nrm, dinv);
  norm_kernel<<<cdiv(kN, BLK), BLK, 0, stream>>>(row_ptr, csr_src, csr_nrm,
                                                 dinv);

  // --- layer 0: propagate in 16-dim, then 16->32 transform (+b0, relu) ---
  propagate_kernel<16, false><<<cdiv(kN * 16, BLK), BLK, 0, stream>>>(
      hA, hB, row_ptr, csr_src, csr_nrm, dinv, nullptr);
  transform_kernel<16, 32, true, true><<<cdiv(kN * 32, BLK), BLK, 0, stream>>>(
      hB, W0, b0, hA);

  // --- layers 1..4: propagate 32-dim, transform 32->32 (+b, relu) ---
  const float* Ws[4] = {W1, W2, W3, W4};
  const float* Bs[4] = {b1, b2, b3, b4};
  for (int l = 0; l < 4; ++l) {
    propagate_kernel<32, false><<<cdiv(kN * 32, BLK), BLK, 0, stream>>>(
        hA, hB, row_ptr, csr_src, csr_nrm, dinv, nullptr);
    transform_kernel<32, 32, true, true>
        <<<cdiv(kN * 32, BLK), BLK, 0, stream>>>(hB, Ws[l], Bs[l], hA);
  }

  // --- layer 5: transform 32->16 first (no bias/relu), then propagate (+b5) ---
  transform_kernel<32, 16, false, false>
      <<<cdiv(kN * 16, BLK), BLK, 0, stream>>>(hA, W5, nullptr, hB);
  propagate_kernel<16, true><<<cdiv(kN * 16, BLK), BLK, 0, stream>>>(
      hB, out, row_ptr, csr_src, csr_nrm, dinv, b5);
}

// Round 4
// 736.093 us; speedup vs baseline: 2.0868x; 1.5787x over previous
//
#include <hip/hip_runtime.h>

// SimpleRecGNN: 6-layer GCN, N=200000 nodes, E=2000000 edges, dims 16->32(x5)->16.
// CSR of combined 8B records {src,w} built per launch (count -> 3-kernel scan ->
// scatter). Per-edge norm computed in-place during layer 0. Each layer is ONE
// fused kernel: gather-propagate (LANES lanes/node, float4 each) + in-wave
// shuffle transform against W in LDS (+bias+ReLU). Layer 4 chains x W5.
// Linearity: agg(hW * norm) == agg(h * norm) W.

namespace {

constexpr int kUsers = 100000;
constexpr int kBooks = 100000;
constexpr int kN = kUsers + kBooks;
constexpr int kE = 2000000;
constexpr int BLK = 256;

constexpr int SCAN_T = 256;
constexpr int SCAN_PER_THREAD = 4;
constexpr int SCAN_ELEMS = SCAN_T * SCAN_PER_THREAD;             // 1024
constexpr int SCAN_BLOCKS = (kN + SCAN_ELEMS - 1) / SCAN_ELEMS;  // 196

__global__ void init_kernel(int* __restrict__ cnt) {
  int stride = gridDim.x * blockDim.x;
  for (int i = blockIdx.x * blockDim.x + threadIdx.x; i < kN; i += stride)
    cnt[i] = 0;
}

// h16[node] = (type==0 ? user_emb[clip(nid)] : book_emb[clip(nid-U)]) ; float4/lane
__global__ void embed_kernel(const int* __restrict__ x,
                             const float* __restrict__ uemb,
                             const float* __restrict__ bemb,
                             float* __restrict__ h) {
  int gid = blockIdx.x * blockDim.x + threadIdx.x;  // exact grid kN*4
  int node = gid >> 2;
  int q = gid & 3;
  if (node >= kN) return;
  int2 xv = ((const int2*)x)[node];
  float4 v;
  if (xv.y == 0) {
    int c = min(max(xv.x, 0), kUsers - 1);
    v = ((const float4*)(uemb + (size_t)c * 16))[q];
  } else {
    int c = min(max(xv.x - kUsers, 0), kBooks - 1);
    v = ((const float4*)(bemb + (size_t)c * 16))[q];
  }
  ((float4*)h)[node * 4 + q] = v;
}

// count in-edges per destination (int4 reads, int atomics)
__global__ void edge_count_kernel(const int* __restrict__ ei_col,
                                  int* __restrict__ cnt) {
  int stride = gridDim.x * blockDim.x;
  constexpr int quarter = kE / 4;
  const int4* col4 = (const int4*)ei_col;
  for (int i = blockIdx.x * blockDim.x + threadIdx.x; i < quarter;
       i += stride) {
    int4 c = col4[i];
    atomicAdd(&cnt[c.x], 1);
    atomicAdd(&cnt[c.y], 1);
    atomicAdd(&cnt[c.z], 1);
    atomicAdd(&cnt[c.w], 1);
  }
}

__global__ void __launch_bounds__(SCAN_T) scan_part_kernel(
    const int* __restrict__ cnt, int* __restrict__ bsum) {
  __shared__ int s[SCAN_T];
  int b = blockIdx.x;
  int t = threadIdx.x;
  int base = b * SCAN_ELEMS + t * SCAN_PER_THREAD;
  int sum = 0;
#pragma unroll
  for (int j = 0; j < SCAN_PER_THREAD; ++j) {
    int i = base + j;
    if (i < kN) sum += cnt[i];
  }
  s[t] = sum;
  __syncthreads();
  for (int off = SCAN_T / 2; off > 0; off >>= 1) {
    if (t < off) s[t] += s[t + off];
    __syncthreads();
  }
  if (t == 0) bsum[b] = s[0];
}

__global__ void __launch_bounds__(SCAN_T) scan_mid_kernel(
    const int* __restrict__ bsum, int* __restrict__ boff,
    int* __restrict__ row_ptr) {
  __shared__ int s[SCAN_T];
  int t = threadIdx.x;
  int v = (t < SCAN_BLOCKS) ? bsum[t] : 0;
  s[t] = v;
  __syncthreads();
  for (int off = 1; off < SCAN_T; off <<= 1) {
    int add = (t >= off) ? s[t - off] : 0;
    __syncthreads();
    s[t] += add;
    __syncthreads();
  }
  if (t < SCAN_BLOCKS) boff[t] = (t == 0) ? 0 : s[t - 1];
  if (t == SCAN_T - 1) row_ptr[kN] = s[SCAN_T - 1];  // == kE
}

__global__ void __launch_bounds__(SCAN_T) scan_final_kernel(
    const int* __restrict__ cnt, const int* __restrict__ boff,
    int* __restrict__ row_ptr, int* __restrict__ fill) {
  __shared__ int s[SCAN_T];
  int b = blockIdx.x;
  int t = threadIdx.x;
  int base = b * SCAN_ELEMS + t * SCAN_PER_THREAD;
  int v[SCAN_PER_THREAD];
  int sum = 0;
#pragma unroll
  for (int j = 0; j < SCAN_PER_THREAD; ++j) {
    int i = base + j;
    v[j] = (i < kN) ? cnt[i] : 0;
    sum += v[j];
  }
  s[t] = sum;
  __syncthreads();
  for (int off = 1; off < SCAN_T; off <<= 1) {
    int add = (t >= off) ? s[t - off] : 0;
    __syncthreads();
    s[t] += add;
    __syncthreads();
  }
  int run = boff[b] + ((t == 0) ? 0 : s[t - 1]);
#pragma unroll
  for (int j = 0; j < SCAN_PER_THREAD; ++j) {
    int i = base + j;
    if (i < kN) {
      row_ptr[i] = run;
      fill[i] = run;
    }
    run += v[j];
  }
}

// scatter edges into CSR records {src, raw_w}; fill[] pre-set to row_ptr.
__global__ void scatter_kernel(const int* __restrict__ ei,
                               const float* __restrict__ ew,
                               int* __restrict__ fill,
                               int2* __restrict__ csr) {
  int stride = gridDim.x * blockDim.x;
  constexpr int quarter = kE / 4;
  const int4* row4 = (const int4*)ei;
  const int4* col4 = (const int4*)(ei + kE);
  const float4* w4p = (const float4*)ew;
  for (int i = blockIdx.x * blockDim.x + threadIdx.x; i < quarter;
       i += stride) {
    int4 r = row4[i];
    int4 c = col4[i];
    float4 w = w4p[i];
    int pos;
    pos = atomicAdd(&fill[c.x], 1);
    csr[pos] = make_int2(r.x, __float_as_int(w.x));
    pos = atomicAdd(&fill[c.y], 1);
    csr[pos] = make_int2(r.y, __float_as_int(w.y));
    pos = atomicAdd(&fill[c.z], 1);
    csr[pos] = make_int2(r.z, __float_as_int(w.z));
    pos = atomicAdd(&fill[c.w], 1);
    csr[pos] = make_int2(r.w, __float_as_int(w.w));
  }
}

// deg = 1 + sum(row w); dinv = rsqrt(deg)
__global__ void deg_dinv_kernel(const int* __restrict__ row_ptr,
                                const int2* __restrict__ csr,
                                float* __restrict__ dinv) {
  int stride = gridDim.x * blockDim.x;
  for (int i = blockIdx.x * blockDim.x + threadIdx.x; i < kN; i += stride) {
    int beg = row_ptr[i];
    int end = row_ptr[i + 1];
    float s = 1.0f;  // self-loop
    for (int e = beg; e < end; ++e) s += __int_as_float(csr[e].y);
    dinv[i] = rsqrtf(fmaxf(s, 1e-12f));
  }
}

// Fused layer: propagate (gather, LANES lanes/node x float4) then in-wave
// shuffle transform z = agg @ W + b (, ReLU)(, chain x W2 32->16).
// FIRST: record.w is raw edge weight; compute norm on the fly and write back.
template <int LANES, int DOUT, bool FIRST, bool RELU, bool CHAIN16>
__global__ void __launch_bounds__(BLK) layer_kernel(
    const float* __restrict__ h, float* __restrict__ outp,
    const int* __restrict__ row_ptr, int2* csr,
    const float* __restrict__ dinv, const float* __restrict__ W,
    const float* __restrict__ bias, const float* __restrict__ W2) {
  constexpr int DIN = LANES * 4;
  constexpr int OPL = DOUT / LANES;  // outputs per lane
  __shared__ float sW[DIN * DOUT];
  __shared__ float sB[DOUT];
  __shared__ float sW2[CHAIN16 ? 32 * 16 : 1];
  for (int i = threadIdx.x; i < DIN * DOUT; i += BLK) sW[i] = W[i];
  for (int i = threadIdx.x; i < DOUT; i += BLK) sB[i] = bias[i];
  if (CHAIN16)
    for (int i = threadIdx.x; i < 32 * 16; i += BLK) sW2[i] = W2[i];
  __syncthreads();

  int gid = blockIdx.x * BLK + threadIdx.x;  // exact grid kN*LANES
  int node = gid / LANES;
  int lane = gid % LANES;
  if (node >= kN) return;
  float di = dinv[node];
  const float4* h4 = (const float4*)h;
  float4 acc = h4[node * LANES + lane];  // self loop * di^2
  float sl = di * di;
  acc.x *= sl;
  acc.y *= sl;
  acc.z *= sl;
  acc.w *= sl;
  int beg = row_ptr[node];
  int end = row_ptr[node + 1];
  for (int e = beg; e < end; ++e) {
    int2 rc = csr[e];
    float nrm;
    if (FIRST) {
      nrm = dinv[rc.x] * __int_as_float(rc.y) * di;
      if (lane == 0) ((float*)csr)[2 * e + 1] = nrm;  // finalize for later layers
    } else {
      nrm = __int_as_float(rc.y);
    }
    float4 hv = h4[rc.x * LANES + lane];
    acc.x = fmaf(hv.x, nrm, acc.x);
    acc.y = fmaf(hv.y, nrm, acc.y);
    acc.z = fmaf(hv.z, nrm, acc.z);
    acc.w = fmaf(hv.w, nrm, acc.w);
  }

  // transform: full DIN-vector lives across the LANES lanes of this node.
  float o[OPL];
#pragma unroll
  for (int j = 0; j < OPL; ++j) o[j] = sB[lane * OPL + j];
  float ax = acc.x, ay = acc.y, az = acc.z, aw = acc.w;
#pragma unroll
  for (int k = 0; k < DIN; ++k) {
    const int c = k & 3;
    float v = (c == 0) ? ax : (c == 1) ? ay : (c == 2) ? az : aw;
    float hk = __shfl(v, k >> 2, LANES);
    const float* wr = &sW[k * DOUT + lane * OPL];
#pragma unroll
    for (int j = 0; j < OPL; ++j) o[j] = fmaf(hk, wr[j], o[j]);
  }
  if (RELU) {
#pragma unroll
    for (int j = 0; j < OPL; ++j) o[j] = fmaxf(o[j], 0.f);
  }
  if (!CHAIN16) {
    float* op = outp + (size_t)node * DOUT + lane * OPL;
#pragma unroll
    for (int j = 0; j < OPL; j += 4)
      *(float4*)(op + j) = make_float4(o[j], o[j + 1], o[j + 2], o[j + 3]);
  } else {
    // second transform 32->16 (LANES==8, OPL==4); out dims [2*lane, 2*lane+2)
    float o2x = 0.f, o2y = 0.f;
#pragma unroll
    for (int k = 0; k < 32; ++k) {
      const int c = k & 3;
      float v = (c == 0) ? o[0] : (c == 1) ? o[1] : (c == 2) ? o[2] : o[3];
      float hk = __shfl(v, k >> 2, 8);
      o2x = fmaf(hk, sW2[k * 16 + lane * 2 + 0], o2x);
      o2y = fmaf(hk, sW2[k * 16 + lane * 2 + 1], o2y);
    }
    *(float2*)(outp + (size_t)node * 16 + lane * 2) = make_float2(o2x, o2y);
  }
}

// final: out = agg(h16) + b5 (no transform, no relu)
__global__ void __launch_bounds__(BLK) final_prop_kernel(
    const float* __restrict__ h, float* __restrict__ out,
    const int* __restrict__ row_ptr, const int2* __restrict__ csr,
    const float* __restrict__ dinv, const float* __restrict__ b5) {
  int gid = blockIdx.x * BLK + threadIdx.x;  // exact grid kN*4
  int node = gid >> 2;
  int q = gid & 3;
  if (node >= kN) return;
  float di = dinv[node];
  const float4* h4 = (const float4*)h;
  float4 acc = h4[node * 4 + q];
  float sl = di * di;
  acc.x *= sl;
  acc.y *= sl;
  acc.z *= sl;
  acc.w *= sl;
  int beg = row_ptr[node];
  int end = row_ptr[node + 1];
  for (int e = beg; e < end; ++e) {
    int2 rc = csr[e];
    float nrm = __int_as_float(rc.y);
    float4 hv = h4[rc.x * 4 + q];
    acc.x = fmaf(hv.x, nrm, acc.x);
    acc.y = fmaf(hv.y, nrm, acc.y);
    acc.z = fmaf(hv.z, nrm, acc.z);
    acc.w = fmaf(hv.w, nrm, acc.w);
  }
  float4 b = ((const float4*)b5)[q];
  acc.x += b.x;
  acc.y += b.y;
  acc.z += b.z;
  acc.w += b.w;
  ((float4*)out)[node * 4 + q] = acc;
}

inline int cdiv(long a, long b) { return (int)((a + b - 1) / b); }

}  // namespace

extern "C" void kernel_launch(void* const* d_in, const int* in_sizes, int n_in,
                              void* d_out, int out_size, void* d_ws,
                              size_t ws_size, hipStream_t stream) {
  const int* x = (const int*)d_in[0];
  const int* ei = (const int*)d_in[1];
  const float* ew = (const float*)d_in[2];
  const float* uemb = (const float*)d_in[3];
  const float* bemb = (const float*)d_in[4];
  const float* W0 = (const float*)d_in[5];
  const float* b0 = (const float*)d_in[6];
  const float* W1 = (const float*)d_in[7];
  const float* b1 = (const float*)d_in[8];
  const float* W2 = (const float*)d_in[9];
  const float* b2 = (const float*)d_in[10];
  const float* W3 = (const float*)d_in[11];
  const float* b3 = (const float*)d_in[12];
  const float* W4 = (const float*)d_in[13];
  const float* b4 = (const float*)d_in[14];
  const float* W5 = (const float*)d_in[15];
  const float* b5 = (const float*)d_in[16];
  float* out = (float*)d_out;

  char* ws = (char*)d_ws;
  size_t off = 0;
  auto walloc = [&](size_t bytes) -> void* {
    void* p = ws + off;
    off += (bytes + 255) & ~size_t(255);
    return p;
  };
  int* row_ptr = (int*)walloc((size_t)(kN + 1) * 4);
  float* dinv = (float*)walloc((size_t)kN * 4);
  int2* csr = (int2*)walloc((size_t)kE * 8);
  float* hE = (float*)walloc((size_t)kN * 16 * 4);  // h16 (embed / chain out)
  float* hA = (float*)walloc((size_t)kN * 32 * 4);
  float* hB = (float*)walloc((size_t)kN * 32 * 4);
  // prep-phase scratch overlaid on hA (hA first written in layer 0, after prep)
  int* cnt = (int*)hA;
  int* fill = cnt + kN;
  int* bsum = fill + kN;
  int* boff = bsum + SCAN_BLOCKS;
  (void)ws_size;
  (void)in_sizes;
  (void)n_in;
  (void)out_size;

  // --- graph prep ---
  init_kernel<<<cdiv(kN, BLK), BLK, 0, stream>>>(cnt);
  embed_kernel<<<kN * 4 / BLK, BLK, 0, stream>>>(x, uemb, bemb, hE);
  edge_count_kernel<<<cdiv(kE / 4, BLK), BLK, 0, stream>>>(ei + kE, cnt);
  scan_part_kernel<<<SCAN_BLOCKS, SCAN_T, 0, stream>>>(cnt, bsum);
  scan_mid_kernel<<<1, SCAN_T, 0, stream>>>(bsum, boff, row_ptr);
  scan_final_kernel<<<SCAN_BLOCKS, SCAN_T, 0, stream>>>(cnt, boff, row_ptr,
                                                        fill);
  scatter_kernel<<<cdiv(kE / 4, BLK), BLK, 0, stream>>>(ei, ew, fill, csr);
  deg_dinv_kernel<<<cdiv(kN, BLK), BLK, 0, stream>>>(row_ptr, csr, dinv);

  // --- fused layers ---
  // L0: h16 -> agg16 -> @W0+b0, relu -> hA (also finalizes csr norms)
  layer_kernel<4, 32, true, true, false><<<kN * 4 / BLK, BLK, 0, stream>>>(
      hE, hA, row_ptr, csr, dinv, W0, b0, nullptr);
  // L1..L3: 32 -> 32
  layer_kernel<8, 32, false, true, false><<<kN * 8 / BLK, BLK, 0, stream>>>(
      hA, hB, row_ptr, csr, dinv, W1, b1, nullptr);
  layer_kernel<8, 32, false, true, false><<<kN * 8 / BLK, BLK, 0, stream>>>(
      hB, hA, row_ptr, csr, dinv, W2, b2, nullptr);
  layer_kernel<8, 32, false, true, false><<<kN * 8 / BLK, BLK, 0, stream>>>(
      hA, hB, row_ptr, csr, dinv, W3, b3, nullptr);
  // L4: 32 -> 32 (relu) then chain x W5 (32->16) -> hE
  layer_kernel<8, 32, false, true, true><<<kN * 8 / BLK, BLK, 0, stream>>>(
      hB, hE, row_ptr, csr, dinv, W4, b4, W5);
  // L5: final propagate of h16 + b5 -> out
  final_prop_kernel<<<kN * 4 / BLK, BLK, 0, stream>>>(hE, out, row_ptr, csr,
                                                      dinv, b5);
}

// Round 6
// 668.559 us; speedup vs baseline: 2.2976x; 1.1010x over previous
//
#include <hip/hip_runtime.h>

// SimpleRecGNN: 6-layer GCN, N=200000 nodes, E=2000000 edges, dims 16->32(x5)->16.
// CSR of combined 8B records {src,w} built per launch. Count & scatter are
// XCD-partitioned: destinations split into 8 ranges; block b handles range b%8
// (round-robin block->XCD), so scattered writes/atomics stay in ONE XCD's L2
// and lines coalesce before writeback (fixes 8x line-granularity write
// amplification). Per-edge norm computed in-place during layer 0. Each layer is
// ONE fused kernel: gather-propagate (LANES lanes/node, float4 each) + in-wave
// shuffle transform vs W in LDS (+bias+ReLU). Layer 4 chains x W5.
// Linearity: agg(hW * norm) == agg(h * norm) W.

namespace {

constexpr int kUsers = 100000;
constexpr int kBooks = 100000;
constexpr int kN = kUsers + kBooks;
constexpr int kE = 2000000;
constexpr int BLK = 256;

constexpr int NPART = 8;                 // dest ranges == XCD count
constexpr int PART_SIZE = kN / NPART;    // 25000 nodes per range
constexpr int PART_BLOCKS = 2048;        // 256 chunks x 8 ranges

constexpr int SCAN_T = 256;
constexpr int SCAN_PER_THREAD = 4;
constexpr int SCAN_ELEMS = SCAN_T * SCAN_PER_THREAD;             // 1024
constexpr int SCAN_BLOCKS = (kN + SCAN_ELEMS - 1) / SCAN_ELEMS;  // 196

__global__ void init_kernel(int* __restrict__ cnt) {
  int stride = gridDim.x * blockDim.x;
  for (int i = blockIdx.x * blockDim.x + threadIdx.x; i < kN; i += stride)
    cnt[i] = 0;
}

// h16[node] = (type==0 ? user_emb[clip(nid)] : book_emb[clip(nid-U)])
__global__ void embed_kernel(const int* __restrict__ x,
                             const float* __restrict__ uemb,
                             const float* __restrict__ bemb,
                             float* __restrict__ h) {
  int gid = blockIdx.x * blockDim.x + threadIdx.x;  // exact grid kN*4
  int node = gid >> 2;
  int q = gid & 3;
  if (node >= kN) return;
  int2 xv = ((const int2*)x)[node];
  float4 v;
  if (xv.y == 0) {
    int c = min(max(xv.x, 0), kUsers - 1);
    v = ((const float4*)(uemb + (size_t)c * 16))[q];
  } else {
    int c = min(max(xv.x - kUsers, 0), kBooks - 1);
    v = ((const float4*)(bemb + (size_t)c * 16))[q];
  }
  ((float4*)h)[node * 4 + q] = v;
}

// XCD-partitioned in-edge count: block b counts dests in range (b%8),
// streaming chunk (b/8) of the col array. Atomics stay L2-local.
__global__ void __launch_bounds__(BLK) edge_count_kernel(
    const int* __restrict__ ei_col, int* __restrict__ cnt) {
  constexpr int quarter = kE / 4;
  constexpr int nchunks = PART_BLOCKS / NPART;
  constexpr int per = (quarter + nchunks - 1) / nchunks;
  int part = blockIdx.x & (NPART - 1);
  int chunk = blockIdx.x >> 3;
  int lo = part * PART_SIZE;
  int hi = lo + PART_SIZE;
  int end = min(quarter, chunk * per + per);
  const int4* col4 = (const int4*)ei_col;
  for (int i = chunk * per + threadIdx.x; i < end; i += BLK) {
    int4 c = col4[i];
    if (c.x >= lo && c.x < hi) atomicAdd(&cnt[c.x], 1);
    if (c.y >= lo && c.y < hi) atomicAdd(&cnt[c.y], 1);
    if (c.z >= lo && c.z < hi) atomicAdd(&cnt[c.z], 1);
    if (c.w >= lo && c.w < hi) atomicAdd(&cnt[c.w], 1);
  }
}

__global__ void __launch_bounds__(SCAN_T) scan_part_kernel(
    const int* __restrict__ cnt, int* __restrict__ bsum) {
  __shared__ int s[SCAN_T];
  int b = blockIdx.x;
  int t = threadIdx.x;
  int base = b * SCAN_ELEMS + t * SCAN_PER_THREAD;
  int sum = 0;
#pragma unroll
  for (int j = 0; j < SCAN_PER_THREAD; ++j) {
    int i = base + j;
    if (i < kN) sum += cnt[i];
  }
  s[t] = sum;
  __syncthreads();
  for (int off = SCAN_T / 2; off > 0; off >>= 1) {
    if (t < off) s[t] += s[t + off];
    __syncthreads();
  }
  if (t == 0) bsum[b] = s[0];
}

__global__ void __launch_bounds__(SCAN_T) scan_mid_kernel(
    const int* __restrict__ bsum, int* __restrict__ boff,
    int* __restrict__ row_ptr) {
  __shared__ int s[SCAN_T];
  int t = threadIdx.x;
  int v = (t < SCAN_BLOCKS) ? bsum[t] : 0;
  s[t] = v;
  __syncthreads();
  for (int off = 1; off < SCAN_T; off <<= 1) {
    int add = (t >= off) ? s[t - off] : 0;
    __syncthreads();
    s[t] += add;
    __syncthreads();
  }
  if (t < SCAN_BLOCKS) boff[t] = (t == 0) ? 0 : s[t - 1];
  if (t == SCAN_T - 1) row_ptr[kN] = s[SCAN_T - 1];  // == kE
}

__global__ void __launch_bounds__(SCAN_T) scan_final_kernel(
    const int* __restrict__ cnt, const int* __restrict__ boff,
    int* __restrict__ row_ptr, int* __restrict__ fill) {
  __shared__ int s[SCAN_T];
  int b = blockIdx.x;
  int t = threadIdx.x;
  int base = b * SCAN_ELEMS + t * SCAN_PER_THREAD;
  int v[SCAN_PER_THREAD];
  int sum = 0;
#pragma unroll
  for (int j = 0; j < SCAN_PER_THREAD; ++j) {
    int i = base + j;
    v[j] = (i < kN) ? cnt[i] : 0;
    sum += v[j];
  }
  s[t] = sum;
  __syncthreads();
  for (int off = 1; off < SCAN_T; off <<= 1) {
    int add = (t >= off) ? s[t - off] : 0;
    __syncthreads();
    s[t] += add;
    __syncthreads();
  }
  int run = boff[b] + ((t == 0) ? 0 : s[t - 1]);
#pragma unroll
  for (int j = 0; j < SCAN_PER_THREAD; ++j) {
    int i = base + j;
    if (i < kN) {
      row_ptr[i] = run;
      fill[i] = run;
    }
    run += v[j];
  }
}

// XCD-partitioned scatter into CSR records {src, raw_w}; fill pre-set to
// row_ptr. Block b writes only dests in range (b%8) -> its CSR slice stays in
// one XCD's L2, lines fill fully before writeback.
__global__ void __launch_bounds__(BLK) scatter_kernel(
    const int* __restrict__ ei, const float* __restrict__ ew,
    int* __restrict__ fill, int2* __restrict__ csr) {
  constexpr int quarter = kE / 4;
  constexpr int nchunks = PART_BLOCKS / NPART;
  constexpr int per = (quarter + nchunks - 1) / nchunks;
  int part = blockIdx.x & (NPART - 1);
  int chunk = blockIdx.x >> 3;
  int lo = part * PART_SIZE;
  int hi = lo + PART_SIZE;
  int end = min(quarter, chunk * per + per);
  const int4* row4 = (const int4*)ei;
  const int4* col4 = (const int4*)(ei + kE);
  const float4* w4p = (const float4*)ew;
  for (int i = chunk * per + threadIdx.x; i < end; i += BLK) {
    int4 c = col4[i];
    bool ix = (c.x >= lo && c.x < hi), iy = (c.y >= lo && c.y < hi);
    bool iz = (c.z >= lo && c.z < hi), iw = (c.w >= lo && c.w < hi);
    if (!(ix | iy | iz | iw)) continue;
    int4 r = row4[i];
    float4 w = w4p[i];
    if (ix) csr[atomicAdd(&fill[c.x], 1)] = make_int2(r.x, __float_as_int(w.x));
    if (iy) csr[atomicAdd(&fill[c.y], 1)] = make_int2(r.y, __float_as_int(w.y));
    if (iz) csr[atomicAdd(&fill[c.z], 1)] = make_int2(r.z, __float_as_int(w.z));
    if (iw) csr[atomicAdd(&fill[c.w], 1)] = make_int2(r.w, __float_as_int(w.w));
  }
}

// deg = 1 + sum(row w); dinv = rsqrt(deg)
__global__ void deg_dinv_kernel(const int* __restrict__ row_ptr,
                                const int2* __restrict__ csr,
                                float* __restrict__ dinv) {
  int stride = gridDim.x * blockDim.x;
  for (int i = blockIdx.x * blockDim.x + threadIdx.x; i < kN; i += stride) {
    int beg = row_ptr[i];
    int end = row_ptr[i + 1];
    float s = 1.0f;  // self-loop
    for (int e = beg; e < end; ++e) s += __int_as_float(csr[e].y);
    dinv[i] = rsqrtf(fmaxf(s, 1e-12f));
  }
}

// Fused layer: propagate (gather, LANES lanes/node x float4) then in-wave
// shuffle transform z = agg @ W + b (, ReLU)(, chain x W2 32->16).
// FIRST: record.w is raw edge weight; compute norm on the fly, write back.
template <int LANES, int DOUT, bool FIRST, bool RELU, bool CHAIN16>
__global__ void __launch_bounds__(BLK) layer_kernel(
    const float* __restrict__ h, float* __restrict__ outp,
    const int* __restrict__ row_ptr, int2* csr,
    const float* __restrict__ dinv, const float* __restrict__ W,
    const float* __restrict__ bias, const float* __restrict__ W2) {
  constexpr int DIN = LANES * 4;
  constexpr int OPL = DOUT / LANES;  // outputs per lane
  __shared__ float sW[DIN * DOUT];
  __shared__ float sB[DOUT];
  __shared__ float sW2[CHAIN16 ? 32 * 16 : 1];
  for (int i = threadIdx.x; i < DIN * DOUT; i += BLK) sW[i] = W[i];
  for (int i = threadIdx.x; i < DOUT; i += BLK) sB[i] = bias[i];
  if (CHAIN16)
    for (int i = threadIdx.x; i < 32 * 16; i += BLK) sW2[i] = W2[i];
  __syncthreads();

  int gid = blockIdx.x * BLK + threadIdx.x;  // exact grid kN*LANES
  int node = gid / LANES;
  int lane = gid % LANES;
  if (node >= kN) return;
  float di = dinv[node];
  const float4* h4 = (const float4*)h;
  float4 acc = h4[node * LANES + lane];  // self loop * di^2
  float sl = di * di;
  acc.x *= sl;
  acc.y *= sl;
  acc.z *= sl;
  acc.w *= sl;
  int beg = row_ptr[node];
  int end = row_ptr[node + 1];
  for (int e = beg; e < end; ++e) {
    int2 rc = csr[e];
    float nrm;
    if (FIRST) {
      nrm = dinv[rc.x] * __int_as_float(rc.y) * di;
      if (lane == 0) ((float*)csr)[2 * e + 1] = nrm;  // finalize for later
    } else {
      nrm = __int_as_float(rc.y);
    }
    float4 hv = h4[rc.x * LANES + lane];
    acc.x = fmaf(hv.x, nrm, acc.x);
    acc.y = fmaf(hv.y, nrm, acc.y);
    acc.z = fmaf(hv.z, nrm, acc.z);
    acc.w = fmaf(hv.w, nrm, acc.w);
  }

  // transform: full DIN-vector lives across the LANES lanes of this node.
  float o[OPL];
#pragma unroll
  for (int j = 0; j < OPL; ++j) o[j] = sB[lane * OPL + j];
  float ax = acc.x, ay = acc.y, az = acc.z, aw = acc.w;
#pragma unroll
  for (int k = 0; k < DIN; ++k) {
    const int c = k & 3;
    float v = (c == 0) ? ax : (c == 1) ? ay : (c == 2) ? az : aw;
    float hk = __shfl(v, k >> 2, LANES);
    const float* wr = &sW[k * DOUT + lane * OPL];
#pragma unroll
    for (int j = 0; j < OPL; ++j) o[j] = fmaf(hk, wr[j], o[j]);
  }
  if (RELU) {
#pragma unroll
    for (int j = 0; j < OPL; ++j) o[j] = fmaxf(o[j], 0.f);
  }
  if (!CHAIN16) {
    float* op = outp + (size_t)node * DOUT + lane * OPL;
#pragma unroll
    for (int j = 0; j < OPL; j += 4)
      *(float4*)(op + j) = make_float4(o[j], o[j + 1], o[j + 2], o[j + 3]);
  } else {
    // second transform 32->16 (LANES==8, OPL==4); out dims [2*lane, 2*lane+2)
    float o2x = 0.f, o2y = 0.f;
#pragma unroll
    for (int k = 0; k < 32; ++k) {
      const int c = k & 3;
      float v = (c == 0) ? o[0] : (c == 1) ? o[1] : (c == 2) ? o[2] : o[3];
      float hk = __shfl(v, k >> 2, 8);
      o2x = fmaf(hk, sW2[k * 16 + lane * 2 + 0], o2x);
      o2y = fmaf(hk, sW2[k * 16 + lane * 2 + 1], o2y);
    }
    *(float2*)(outp + (size_t)node * 16 + lane * 2) = make_float2(o2x, o2y);
  }
}

// final: out = agg(h16) + b5 (no transform, no relu)
__global__ void __launch_bounds__(BLK) final_prop_kernel(
    const float* __restrict__ h, float* __restrict__ out,
    const int* __restrict__ row_ptr, const int2* __restrict__ csr,
    const float* __restrict__ dinv, const float* __restrict__ b5) {
  int gid = blockIdx.x * BLK + threadIdx.x;  // exact grid kN*4
  int node = gid >> 2;
  int q = gid & 3;
  if (node >= kN) return;
  float di = dinv[node];
  const float4* h4 = (const float4*)h;
  float4 acc = h4[node * 4 + q];
  float sl = di * di;
  acc.x *= sl;
  acc.y *= sl;
  acc.z *= sl;
  acc.w *= sl;
  int beg = row_ptr[node];
  int end = row_ptr[node + 1];
  for (int e = beg; e < end; ++e) {
    int2 rc = csr[e];
    float nrm = __int_as_float(rc.y);
    float4 hv = h4[rc.x * 4 + q];
    acc.x = fmaf(hv.x, nrm, acc.x);
    acc.y = fmaf(hv.y, nrm, acc.y);
    acc.z = fmaf(hv.z, nrm, acc.z);
    acc.w = fmaf(hv.w, nrm, acc.w);
  }
  float4 b = ((const float4*)b5)[q];
  acc.x += b.x;
  acc.y += b.y;
  acc.z += b.z;
  acc.w += b.w;
  ((float4*)out)[node * 4 + q] = acc;
}

inline int cdiv(long a, long b) { return (int)((a + b - 1) / b); }

}  // namespace

extern "C" void kernel_launch(void* const* d_in, const int* in_sizes, int n_in,
                              void* d_out, int out_size, void* d_ws,
                              size_t ws_size, hipStream_t stream) {
  const int* x = (const int*)d_in[0];
  const int* ei = (const int*)d_in[1];
  const float* ew = (const float*)d_in[2];
  const float* uemb = (const float*)d_in[3];
  const float* bemb = (const float*)d_in[4];
  const float* W0 = (const float*)d_in[5];
  const float* b0 = (const float*)d_in[6];
  const float* W1 = (const float*)d_in[7];
  const float* b1 = (const float*)d_in[8];
  const float* W2 = (const float*)d_in[9];
  const float* b2 = (const float*)d_in[10];
  const float* W3 = (const float*)d_in[11];
  const float* b3 = (const float*)d_in[12];
  const float* W4 = (const float*)d_in[13];
  const float* b4 = (const float*)d_in[14];
  const float* W5 = (const float*)d_in[15];
  const float* b5 = (const float*)d_in[16];
  float* out = (float*)d_out;

  char* ws = (char*)d_ws;
  size_t off = 0;
  auto walloc = [&](size_t bytes) -> void* {
    void* p = ws + off;
    off += (bytes + 255) & ~size_t(255);
    return p;
  };
  int* row_ptr = (int*)walloc((size_t)(kN + 1) * 4);
  float* dinv = (float*)walloc((size_t)kN * 4);
  int2* csr = (int2*)walloc((size_t)kE * 8);
  float* hE = (float*)walloc((size_t)kN * 16 * 4);  // h16 (embed / chain out)
  float* hA = (float*)walloc((size_t)kN * 32 * 4);
  float* hB = (float*)walloc((size_t)kN * 32 * 4);
  // prep-phase scratch overlaid on hA (hA first written in layer 0, after prep)
  int* cnt = (int*)hA;
  int* fill = cnt + kN;
  int* bsum = fill + kN;
  int* boff = bsum + SCAN_BLOCKS;
  (void)ws_size;
  (void)in_sizes;
  (void)n_in;
  (void)out_size;

  // --- graph prep ---
  init_kernel<<<cdiv(kN, BLK), BLK, 0, stream>>>(cnt);
  embed_kernel<<<kN * 4 / BLK, BLK, 0, stream>>>(x, uemb, bemb, hE);
  edge_count_kernel<<<PART_BLOCKS, BLK, 0, stream>>>(ei + kE, cnt);
  scan_part_kernel<<<SCAN_BLOCKS, SCAN_T, 0, stream>>>(cnt, bsum);
  scan_mid_kernel<<<1, SCAN_T, 0, stream>>>(bsum, boff, row_ptr);
  scan_final_kernel<<<SCAN_BLOCKS, SCAN_T, 0, stream>>>(cnt, boff, row_ptr,
                                                        fill);
  scatter_kernel<<<PART_BLOCKS, BLK, 0, stream>>>(ei, ew, fill, csr);
  deg_dinv_kernel<<<cdiv(kN, BLK), BLK, 0, stream>>>(row_ptr, csr, dinv);

  // --- fused layers ---
  // L0: h16 -> agg16 -> @W0+b0, relu -> hA (also finalizes csr norms)
  layer_kernel<4, 32, true, true, false><<<kN * 4 / BLK, BLK, 0, stream>>>(
      hE, hA, row_ptr, csr, dinv, W0, b0, nullptr);
  // L1..L3: 32 -> 32
  layer_kernel<8, 32, false, true, false><<<kN * 8 / BLK, BLK, 0, stream>>>(
      hA, hB, row_ptr, csr, dinv, W1, b1, nullptr);
  layer_kernel<8, 32, false, true, false><<<kN * 8 / BLK, BLK, 0, stream>>>(
      hB, hA, row_ptr, csr, dinv, W2, b2, nullptr);
  layer_kernel<8, 32, false, true, false><<<kN * 8 / BLK, BLK, 0, stream>>>(
      hA, hB, row_ptr, csr, dinv, W3, b3, nullptr);
  // L4: 32 -> 32 (relu) then chain x W5 (32->16) -> hE
  layer_kernel<8, 32, false, true, true><<<kN * 8 / BLK, BLK, 0, stream>>>(
      hB, hE, row_ptr, csr, dinv, W4, b4, W5);
  // L5: final propagate of h16 + b5 -> out
  final_prop_kernel<<<kN * 4 / BLK, BLK, 0, stream>>>(hE, out, row_ptr, csr,
                                                      dinv, b5);
}